// Round 11
// baseline (786.818 us; speedup 1.0000x reference)
//
#include <hip/hip_runtime.h>

// NCC forward: X,Y (16,32,64,24) fp32, PS=5, D=2, EPS=0.01
// out[blk*184320 + (yo*24+i)*1536 + h*24 + x] =
//   (cross - Em(h,x)*SF(h+yo,i)) * IE(h,x) * IF(h+yo,i)
// cross = sum_{dy,dx} Xp[h+dy][x+dx] * Yp[h+yo+dy][i+dx]
//
// R5/R9 occupancy identity kept: 512 blocks x 576 thr = 9 waves,
// launch_bounds(576,5) -> VGPR<=102 -> 2 blocks/CU = 18 waves/CU.
// R10 change (store-MLP): thread owns TWO flat positions p=2*tid, 2*tid+1
// (x even, pair in-row) -> float2 stores = 512B contiguous per wave, 2.5KB
// in flight per wave-step (2x R9). yw window shared by both x -> per-output
// LDS halves too. 2 h-tiles (48 + 16 rows); tile 2 retires waves 3..8.
// Y staged in parity-shifted duplicate columns (sYe/sYo) so the 9-row roll
// is 5x ds_read_b64 for both h parities (R9 trick).

#define NT 576

template<int K>
__device__ __forceinline__ void step_i(
    int i,
    const float2* __restrict__ pbY, const float2* __restrict__ pbF,
    const float (&Xw)[5][6], float (&yw)[9][5],
    const float (&Em)[2], const float (&IE)[2],
    float* __restrict__ outT)
{
    // roll in Yp column i+4, rows h..h+8: 5x b64 (10th float unused)
    const float2* q = pbY + (i + 4) * 37;
    float2 t0 = q[0], t1 = q[1], t2 = q[2], t3 = q[3], t4 = q[4];
    constexpr int s4 = (K + 4) % 5;
    yw[0][s4] = t0.x; yw[1][s4] = t0.y;
    yw[2][s4] = t1.x; yw[3][s4] = t1.y;
    yw[4][s4] = t2.x; yw[5][s4] = t2.y;
    yw[6][s4] = t3.x; yw[7][s4] = t3.y;
    yw[8][s4] = t4.x;

    // cross for 2 x-positions x 5 yo: 250 FMA, all register operands
    float cr0[5] = {0.f, 0.f, 0.f, 0.f, 0.f};
    float cr1[5] = {0.f, 0.f, 0.f, 0.f, 0.f};
    #pragma unroll
    for (int dy = 0; dy < 5; ++dy) {
        #pragma unroll
        for (int dx = 0; dx < 5; ++dx) {
            #pragma unroll
            for (int yo = 0; yo < 5; ++yo) {
                const float yv = yw[dy + yo][(K + dx) % 5];
                cr0[yo] = fmaf(Xw[dy][dx],     yv, cr0[yo]);
                cr1[yo] = fmaf(Xw[dy][dx + 1], yv, cr1[yo]);
            }
        }
    }

    // (SF, 1/Fs) rows h..h+4 at col i: 5x aligned b64; emit 5 float2 stores
    const float2* fp = pbF + i * 68;
    #pragma unroll
    for (int yo = 0; yo < 5; ++yo) {
        float2 f = fp[yo];
        float2 v;
        v.x = fmaf(-Em[0], f.x, cr0[yo]) * (IE[0] * f.y);
        v.y = fmaf(-Em[1], f.x, cr1[yo]) * (IE[1] * f.y);
        *(float2*)(outT + (size_t)(yo * 24 + i) * 1536) = v;
    }
}

__global__ __launch_bounds__(NT, 5)
void ncc_kernel(const float* __restrict__ X, const float* __restrict__ Y,
                float* __restrict__ out)
{
    __shared__ __align__(16) float sXp[68 * 28];     // Xp row-major, rows 0..67
    __shared__ __align__(16) float sYe[28 * 74];     // Yp col-major [c][r], stride 74
    __shared__ __align__(16) float sYo[28 * 74];     // shifted: [c*74 + r-1] = Yp[c][r]
    __shared__ __align__(16) float sMI[64 * 24 * 2]; // (Em, IE) per (h,x)
    __shared__ __align__(16) float sFI[24 * 68 * 2]; // (SF, 1/Fs) per (i, r)

    const int tid = threadIdx.x;
    const int blk = blockIdx.x;            // = b*32 + c
    const float* Xc = X + (size_t)blk * 1536;
    const float* Yc = Y + (size_t)blk * 1536;
    float* outC = out + (size_t)blk * 184320;

    // ---- Phase A: stage padded inputs (Y into both parity copies) ----
    for (int idx = tid; idx < 68 * 28; idx += NT) {
        int r = idx / 28, cc = idx - r * 28;
        int hh = r - 2, ww = cc - 2;
        float v = 0.f;
        if ((unsigned)hh < 64u && (unsigned)ww < 24u) v = Xc[hh * 24 + ww];
        sXp[idx] = v;
    }
    for (int idx = tid; idx < 72 * 28; idx += NT) {
        int r = idx / 28, cc = idx - r * 28;
        int hh = r - 4, ww = cc - 2;
        float v = 0.f;
        if ((unsigned)hh < 64u && (unsigned)ww < 24u) v = Yc[hh * 24 + ww];
        sYe[cc * 74 + r] = v;
        if (r > 0) sYo[cc * 74 + r - 1] = v;
    }
    __syncthreads();

    // ---- Phase B: patch statistics ----
    for (int idx = tid; idx < 64 * 24; idx += NT) {          // X stats -> sMI
        int hl = idx / 24, xx = idx - hl * 24;
        float s = 0.f, s2 = 0.f;
        #pragma unroll
        for (int dy = 0; dy < 5; ++dy)
            #pragma unroll
            for (int dx = 0; dx < 5; ++dx) {
                float v = sXp[(hl + dy) * 28 + xx + dx];
                s += v; s2 = fmaf(v, v, s2);
            }
        float var = fmaxf((s2 - s * s * 0.04f) * (1.f / 24.f), 0.f);
        sMI[idx * 2]     = s * 0.04f;                           // Em
        sMI[idx * 2 + 1] = 1.f / (25.f * (sqrtf(var) + 0.01f)); // 1/(25*Es)
    }
    for (int idx = tid; idx < 24 * 68; idx += NT) {          // Y stats -> sFI
        int ii = idx / 68, r = idx - ii * 68;
        float s = 0.f, s2 = 0.f;
        #pragma unroll
        for (int dx = 0; dx < 5; ++dx)
            #pragma unroll
            for (int dy = 0; dy < 5; ++dy) {
                float v = sYe[(ii + dx) * 74 + r + dy];
                s += v; s2 = fmaf(v, v, s2);
            }
        float var = fmaxf((s2 - s * s * 0.04f) * (1.f / 24.f), 0.f);
        int be = (ii * 68 + r) * 2;
        sFI[be]     = s;                                // SF (patch sum)
        sFI[be + 1] = 1.f / (sqrtf(var) + 0.01f);       // 1/Fs
    }
    __syncthreads();

    // ---- Phase C: 2 h-tiles x 24 i-steps; thread owns p = 2*tid (+1) ----
    const int x2   = tid % 12;
    const int hrel = tid / 12;             // 0..47
    const int x    = x2 * 2;               // even

    #pragma unroll 1
    for (int t2 = 0; t2 < 2; ++t2) {
        const int h = t2 * 48 + hrel;
        if (h >= 64) break;                // tile 2: waves 3..8 retire (uniform)
        const int lo = h * 24 + x;         // = 2*tid (tile 1) — flat, wave-contiguous

        float4 mi = *(const float4*)&sMI[lo * 2];   // (Em0,IE0,Em1,IE1), 16B aligned
        float Em[2] = {mi.x, mi.z};
        float IE[2] = {mi.y, mi.w};

        // parity-selected aligned base pointers (setup-only cost)
        const float2* pbY = (h & 1) ? (const float2*)sYo + ((h - 1) >> 1)
                                    : (const float2*)sYe + (h >> 1);
        const float2* pbF = (const float2*)sFI + h;  // row h+yo = pbF + i*68 + yo

        float Xw[5][6];                   // Xp rows h..h+4, cols x..x+5 (x even)
        #pragma unroll
        for (int dy = 0; dy < 5; ++dy) {
            const float2* xr = (const float2*)&sXp[(h + dy) * 28 + x];
            float2 a = xr[0], bxx = xr[1], cxx = xr[2];
            Xw[dy][0] = a.x;   Xw[dy][1] = a.y;
            Xw[dy][2] = bxx.x; Xw[dy][3] = bxx.y;
            Xw[dy][4] = cxx.x; Xw[dy][5] = cxx.y;
        }

        float yw[9][5];                   // Yp rows h..h+8, rolling col slots
        #pragma unroll
        for (int c = 0; c < 4; ++c) {     // prefill cols 0..3 -> slots 0..3
            const float2* q = pbY + c * 37;
            float2 t0 = q[0], t1 = q[1], t2v = q[2], t3 = q[3], t4 = q[4];
            yw[0][c] = t0.x;  yw[1][c] = t0.y;
            yw[2][c] = t1.x;  yw[3][c] = t1.y;
            yw[4][c] = t2v.x; yw[5][c] = t2v.y;
            yw[6][c] = t3.x;  yw[7][c] = t3.y;
            yw[8][c] = t4.x;
        }

        float* outT = outC + lo;

        #pragma unroll 1
        for (int t5 = 0; t5 < 20; t5 += 5) {
            step_i<0>(t5 + 0, pbY, pbF, Xw, yw, Em, IE, outT);
            step_i<1>(t5 + 1, pbY, pbF, Xw, yw, Em, IE, outT);
            step_i<2>(t5 + 2, pbY, pbF, Xw, yw, Em, IE, outT);
            step_i<3>(t5 + 3, pbY, pbF, Xw, yw, Em, IE, outT);
            step_i<4>(t5 + 4, pbY, pbF, Xw, yw, Em, IE, outT);
        }
        step_i<0>(20, pbY, pbF, Xw, yw, Em, IE, outT);
        step_i<1>(21, pbY, pbF, Xw, yw, Em, IE, outT);
        step_i<2>(22, pbY, pbF, Xw, yw, Em, IE, outT);
        step_i<3>(23, pbY, pbF, Xw, yw, Em, IE, outT);
    }
}

extern "C" void kernel_launch(void* const* d_in, const int* in_sizes, int n_in,
                              void* d_out, int out_size, void* d_ws, size_t ws_size,
                              hipStream_t stream) {
    const float* X = (const float*)d_in[0];
    const float* Y = (const float*)d_in[1];
    float* out = (float*)d_out;
    ncc_kernel<<<dim3(16 * 32), dim3(NT), 0, stream>>>(X, Y, out);
}